// Round 8
// baseline (746.761 us; speedup 1.0000x reference)
//
#include <hip/hip_runtime.h>
#include <math.h>

#define NROWS 50000
#define DIN   3000
#define FH1   100
#define FH2   20
#define GH1   32
#define GH2   8
#define KCL   10
#define LAT   28
#define NEDGE 800000

static __device__ __forceinline__ float elu1(float v) {
  return v > 0.f ? v : (__expf(v) - 1.f);
}

static __device__ __forceinline__ unsigned short f2bf(float f) {
  unsigned int u = __float_as_uint(f);
  unsigned int r = (u + 0x7FFFu + ((u >> 16) & 1u)) >> 16;
  return (unsigned short)r;
}

#define BN_RS 0.99995000374968754f  /* 1/sqrt(1+1e-4) */

typedef __attribute__((ext_vector_type(8))) short bf16x8_t;
typedef __attribute__((ext_vector_type(4))) float f32x4_t;

// async global->LDS, 16B per lane, dest = wave-uniform base + lane*16
#define GLL(gp, lp)                                                              \
  __builtin_amdgcn_global_load_lds(                                              \
      (const __attribute__((address_space(1))) void*)(gp),                       \
      (__attribute__((address_space(3))) void*)(lp), 16, 0, 0)

// ---------------- prep: Wt[n][k] = bf16(W1[k][n]), n<112 (pad0), k<3008 (pad0) ----------------
__global__ __launch_bounds__(256) void k_prepW(const float* __restrict__ W,
                                               unsigned short* __restrict__ Wt) {
  const int idx = blockIdx.x * 256 + threadIdx.x;   // 112*376 chunks of 8
  const int n = idx / 376;
  const int kc = (idx - n * 376) * 8;
  if (n >= 112) return;
  unsigned short v[8];
#pragma unroll
  for (int j = 0; j < 8; ++j) {
    const int k = kc + j;
    const float f = (n < FH1 && k < DIN) ? W[(size_t)k * FH1 + n] : 0.f;
    v[j] = f2bf(f);
  }
  uint4 pv;
  pv.x = (unsigned)v[0] | ((unsigned)v[1] << 16);
  pv.y = (unsigned)v[2] | ((unsigned)v[3] << 16);
  pv.z = (unsigned)v[4] | ((unsigned)v[5] << 16);
  pv.w = (unsigned)v[6] | ((unsigned)v[7] << 16);
  *(uint4*)&Wt[(size_t)n * 3008 + kc] = pv;
}

// ---------------- GEMM1 v7: counted-vmcnt 3-buffer gload_lds pipeline (T3/T4) ----------------
// BK=32; A fp32 [64][32] (8KB) + B bf16 [128][32] (8KB, rows 112-127 staged-never-read)
// = 16KB/buffer x3 = 48KB -> 3 blocks/CU. 4 gload_lds per wave per tile (uniform) ->
// per-iter wait = vmcnt(4) (tile t done, t+1 in flight). Raw s_barrier (no drain).
// A-tail branchless: source k-offset clamps to 2996; garbage k>=3000 multiplies B=0.
__global__ __launch_bounds__(256) void k_gemm1(
    const float* __restrict__ x, const unsigned short* __restrict__ Wt,
    const float* __restrict__ b1, const float* __restrict__ g1, const float* __restrict__ bb1,
    float* __restrict__ out)
{
  __shared__ float Af[3 * 2048];            // 3 x [64][32] fp32
  __shared__ unsigned short Bf[3 * 4096];   // 3 x [128][32] bf16

  const int tid = threadIdx.x;
  const int w = tid >> 6, lane = tid & 63;
  const int fr = lane & 15;
  const int fk = (lane >> 4) * 8;           // 0,8,16,24
  const int rowBase = blockIdx.x * 64;

  f32x4_t acc[7];
#pragma unroll
  for (int f = 0; f < 7; ++f) acc[f] = (f32x4_t){0.f, 0.f, 0.f, 0.f};

  // A: 8 chunks of 1KB; wave w -> chunks {2w, 2w+1}. chunk c: row = c*8+(lane>>3),
  // piece v = lane&7, swz u = v^(row&7). Source pre-swizzled, LDS linear.
  // B: 8 chunks of 1KB; wave w -> chunks {w, w+4}. chunk c: n = c*16+(lane>>2),
  // piece v = lane&3, swz u = v^(n&3).
#define STAGE(bb, tt)                                                            \
  {                                                                              \
    _Pragma("unroll")                                                            \
    for (int i = 0; i < 2; ++i) {                                                \
      const int c_ = w * 2 + i;                                                  \
      const int rl_ = c_ * 8 + (lane >> 3);                                      \
      const int u_ = (lane & 7) ^ (rl_ & 7);                                     \
      const int rg_ = (rowBase + rl_ < NROWS) ? rowBase + rl_ : (NROWS - 1);     \
      int ko_ = (tt) * 32 + u_ * 4;                                              \
      if (ko_ > 2996) ko_ = 2996;  /* in-bounds; B=0 beyond k=2999 */            \
      GLL(x + (size_t)rg_ * DIN + ko_, (char*)Af + (bb) * 8192 + c_ * 1024);     \
    }                                                                            \
    _Pragma("unroll")                                                            \
    for (int i = 0; i < 2; ++i) {                                                \
      const int c_ = w + i * 4;                                                  \
      const int n_ = c_ * 16 + (lane >> 2);                                      \
      const int u_ = (lane & 3) ^ (n_ & 3);                                      \
      GLL(Wt + (size_t)n_ * 3008 + (tt) * 32 + u_ * 8,                           \
          (char*)Bf + (bb) * 8192 + c_ * 1024);                                  \
    }                                                                            \
  }

  // compute one tile from buffer bb
#define COMPUTE(bb)                                                              \
  {                                                                              \
    const int r_ = w * 16 + fr;                                                  \
    const int u0_ = fk >> 2;                                                     \
    const float4 p_ = *(const float4*)&Af[(bb) * 2048 + r_ * 32 +                \
                                          ((u0_ ^ (r_ & 7)) & 7) * 4 +           \
                                          (u0_ & 8) * 4];                        \
    const float4 q_ = *(const float4*)&Af[(bb) * 2048 + r_ * 32 +                \
                                          (((u0_ + 1) ^ (r_ & 7)) & 7) * 4 +     \
                                          ((u0_ + 1) & 8) * 4];                  \
    uint4 av_;                                                                   \
    av_.x = (unsigned)f2bf(p_.x) | ((unsigned)f2bf(p_.y) << 16);                 \
    av_.y = (unsigned)f2bf(p_.z) | ((unsigned)f2bf(p_.w) << 16);                 \
    av_.z = (unsigned)f2bf(q_.x) | ((unsigned)f2bf(q_.y) << 16);                 \
    av_.w = (unsigned)f2bf(q_.z) | ((unsigned)f2bf(q_.w) << 16);                 \
    const bf16x8_t a_ = *(const bf16x8_t*)&av_;                                  \
    _Pragma("unroll")                                                            \
    for (int f = 0; f < 7; ++f) {                                                \
      const int n_ = f * 16 + fr;                                                \
      const int vb_ = (fk >> 3) ^ (n_ & 3);                                      \
      const bf16x8_t b_ = *(const bf16x8_t*)&Bf[(bb) * 4096 + n_ * 32 + vb_ * 8];\
      acc[f] = __builtin_amdgcn_mfma_f32_16x16x32_bf16(a_, b_, acc[f], 0, 0, 0); \
    }                                                                            \
  }

  STAGE(0, 0)
  STAGE(1, 1)

  int c0 = 0;   // buffer holding tile t
  for (int t = 0; t < 93; ++t) {
    asm volatile("s_waitcnt vmcnt(4)" ::: "memory");   // tile t loaded; t+1 in flight
    __builtin_amdgcn_s_barrier();
    __builtin_amdgcn_sched_barrier(0);
    COMPUTE(c0)
    __builtin_amdgcn_sched_barrier(0);
    __builtin_amdgcn_s_barrier();                      // all waves done reading buf c0-1 region
    if (t < 92) {
      const int nb = (c0 + 2 >= 3) ? c0 - 1 : c0 + 2;
      STAGE(nb, t + 2)
    }
    c0 = (c0 + 1 == 3) ? 0 : c0 + 1;
  }
  asm volatile("s_waitcnt vmcnt(0)" ::: "memory");     // last tile (93) fully loaded
  __builtin_amdgcn_s_barrier();
  __builtin_amdgcn_sched_barrier(0);
  COMPUTE(c0)
#undef STAGE
#undef COMPUTE

  // epilogue: C/D layout col=lane&15, row=(lane>>4)*4+reg
  const int s4 = (lane >> 4) * 4;
#pragma unroll
  for (int f = 0; f < 7; ++f) {
    const int col = f * 16 + fr;
    if (col < FH1) {
      const float sc = g1[col] * BN_RS;
      const float bbv = bb1[col];
      const float bv = b1[col];
#pragma unroll
      for (int j = 0; j < 4; ++j) {
        const int row = rowBase + w * 16 + s4 + j;
        if (row < NROWS)
          out[(size_t)row * FH1 + col] = elu1((acc[f][j] + bv) * sc + bbv);
      }
    }
  }
}

// ---------------- feat_x = ELU(BN(feat1 @ W2 + b2)); t1 = feat_x @ gc1_W ----------------
__global__ __launch_bounds__(256) void k_enc2_gc1(
    const float* __restrict__ feat1, const float* __restrict__ W2, const float* __restrict__ b2,
    const float* __restrict__ g2, const float* __restrict__ bb2,
    const float* __restrict__ gc1W,
    float* __restrict__ fx_out, float* __restrict__ t1_out)
{
  const int row = blockIdx.x * blockDim.x + threadIdx.x;
  if (row >= NROWS) return;
  float f1[FH1];
  const float4* fr = (const float4*)(feat1 + (size_t)row * FH1);
#pragma unroll
  for (int i = 0; i < FH1/4; ++i) ((float4*)f1)[i] = fr[i];

  float fx[FH2];
#pragma unroll
  for (int j = 0; j < FH2; ++j) fx[j] = b2[j];
#pragma unroll
  for (int k = 0; k < FH1; ++k) {
    const float f = f1[k];
#pragma unroll
    for (int j = 0; j < FH2; ++j) fx[j] = fmaf(f, W2[k*FH2 + j], fx[j]);
  }
#pragma unroll
  for (int j = 0; j < FH2; ++j) fx[j] = elu1(fx[j] * (g2[j] * BN_RS) + bb2[j]);

  float4* fo = (float4*)(fx_out + (size_t)row * FH2);
#pragma unroll
  for (int i = 0; i < FH2/4; ++i) fo[i] = ((float4*)fx)[i];

  float t[GH1];
#pragma unroll
  for (int j = 0; j < GH1; ++j) t[j] = 0.f;
#pragma unroll
  for (int k = 0; k < FH2; ++k) {
    const float f = fx[k];
#pragma unroll
    for (int j = 0; j < GH1; ++j) t[j] = fmaf(f, gc1W[k*GH1 + j], t[j]);
  }
  float4* to = (float4*)(t1_out + (size_t)row * GH1);
#pragma unroll
  for (int i = 0; i < GH1/4; ++i) to[i] = ((float4*)t)[i];
}

// ---------------- CSR build: zero -> hist -> scan -> scatter ----------------
__global__ void k_zero_i(int* __restrict__ p, int n) {
  for (int i = blockIdx.x * blockDim.x + threadIdx.x; i < n; i += gridDim.x * blockDim.x)
    p[i] = 0;
}

__global__ void k_hist(const int* __restrict__ er, int* __restrict__ deg) {
  const int e = blockIdx.x * 256 + threadIdx.x;
  if (e < NEDGE) atomicAdd(&deg[er[e]], 1);
}

__global__ __launch_bounds__(1024) void k_scan(const int* __restrict__ deg,
                                               int* __restrict__ start) {
  __shared__ int sm[1024];
  const int t = threadIdx.x;
  const int c0 = t * 49;
  const int c1 = (c0 + 49 < NROWS) ? c0 + 49 : NROWS;
  int s = 0;
  for (int i = c0; i < c1; ++i) s += deg[i];
  sm[t] = s;
  __syncthreads();
  for (int off = 1; off < 1024; off <<= 1) {
    int v = (t >= off) ? sm[t - off] : 0;
    __syncthreads();
    sm[t] += v;
    __syncthreads();
  }
  int run = (t == 0) ? 0 : sm[t - 1];
  for (int i = c0; i < c1; ++i) { start[i] = run; run += deg[i]; }
  if (t == 0) start[NROWS] = NEDGE;
}

__global__ void k_scatter(const int* __restrict__ er, const int* __restrict__ ec,
                          const float* __restrict__ vals, const int* __restrict__ start,
                          int* __restrict__ cnt, int* __restrict__ colS,
                          float* __restrict__ valS) {
  const int e = blockIdx.x * 256 + threadIdx.x;
  if (e >= NEDGE) return;
  const int r = er[e];
  const int pos = start[r] + atomicAdd(&cnt[r], 1);
  colS[pos] = ec[e];
  valS[pos] = vals[e];
}

// ---------------- spmm1 gather: h1[r] = sum_j val*t1[col], 8 thr/row ----------------
__global__ __launch_bounds__(256) void k_spmm1g(
    const int* __restrict__ start, const int* __restrict__ colS, const float* __restrict__ valS,
    const float* __restrict__ t1, float* __restrict__ h1)
{
  const int tid = threadIdx.x;
  const int row = blockIdx.x * 32 + (tid >> 3);
  const int p = tid & 7;
  if (row >= NROWS) return;
  const int s = start[row], e = start[row + 1];
  float4 acc = make_float4(0.f, 0.f, 0.f, 0.f);
  for (int j = s; j < e; ++j) {
    const int c = colS[j];
    const float v = valS[j];
    const float4 tv = *(const float4*)&t1[(size_t)c * GH1 + p * 4];
    acc.x = fmaf(v, tv.x, acc.x);
    acc.y = fmaf(v, tv.y, acc.y);
    acc.z = fmaf(v, tv.z, acc.z);
    acc.w = fmaf(v, tv.w, acc.w);
  }
  *(float4*)&h1[(size_t)row * GH1 + p * 4] = acc;
}

// ---------------- mu_pre/lv_pre = relu(h1) @ gc2W / gc3W ----------------
__global__ __launch_bounds__(256) void k_h1gc(
    const float* __restrict__ h1, const float* __restrict__ gc2W, const float* __restrict__ gc3W,
    float* __restrict__ mp, float* __restrict__ lp)
{
  const int row = blockIdx.x * blockDim.x + threadIdx.x;
  if (row >= NROWS) return;
  float h[GH1];
  const float4* hr = (const float4*)(h1 + (size_t)row * GH1);
#pragma unroll
  for (int i = 0; i < GH1/4; ++i) ((float4*)h)[i] = hr[i];
#pragma unroll
  for (int k = 0; k < GH1; ++k) h[k] = fmaxf(h[k], 0.f);

  float m[GH2], l[GH2];
#pragma unroll
  for (int j = 0; j < GH2; ++j) { m[j] = 0.f; l[j] = 0.f; }
#pragma unroll
  for (int k = 0; k < GH1; ++k) {
    const float hv = h[k];
#pragma unroll
    for (int j = 0; j < GH2; ++j) {
      m[j] = fmaf(hv, gc2W[k*GH2 + j], m[j]);
      l[j] = fmaf(hv, gc3W[k*GH2 + j], l[j]);
    }
  }
  float4* mo = (float4*)(mp + (size_t)row * GH2);
  float4* lo = (float4*)(lp + (size_t)row * GH2);
  mo[0] = ((float4*)m)[0]; mo[1] = ((float4*)m)[1];
  lo[0] = ((float4*)l)[0]; lo[1] = ((float4*)l)[1];
}

// ---------------- spmm2 gather: mu/lv, 4 thr/row ----------------
__global__ __launch_bounds__(256) void k_spmm2g(
    const int* __restrict__ start, const int* __restrict__ colS, const float* __restrict__ valS,
    const float* __restrict__ mp, const float* __restrict__ lp,
    float* __restrict__ mu, float* __restrict__ lv)
{
  const int tid = threadIdx.x;
  const int row = blockIdx.x * 64 + (tid >> 2);
  const int p = tid & 3;
  if (row >= NROWS) return;
  const float* src = (p < 2) ? mp : lp;
  float* dst = (p < 2) ? mu : lv;
  const int off = (p & 1) * 4;
  const int s = start[row], e = start[row + 1];
  float4 acc = make_float4(0.f, 0.f, 0.f, 0.f);
  for (int j = s; j < e; ++j) {
    const int c = colS[j];
    const float v = valS[j];
    const float4 sv = *(const float4*)&src[(size_t)c * GH2 + off];
    acc.x = fmaf(v, sv.x, acc.x);
    acc.y = fmaf(v, sv.y, acc.y);
    acc.z = fmaf(v, sv.z, acc.z);
    acc.w = fmaf(v, sv.w, acc.w);
  }
  *(float4*)&dst[(size_t)row * GH2 + off] = acc;
}

// ---------------- z = [feat_x | mu]; gnn_z = mu; q = student-t ----------------
__global__ __launch_bounds__(256) void k_zq(
    const float* __restrict__ fx, const float* __restrict__ mu, const float* __restrict__ clus,
    float* __restrict__ z_o, float* __restrict__ gz_o, float* __restrict__ q_o)
{
  const int row = blockIdx.x * blockDim.x + threadIdx.x;
  if (row >= NROWS) return;
  float z[LAT];
  const float4* f4 = (const float4*)(fx + (size_t)row * FH2);
#pragma unroll
  for (int i = 0; i < FH2/4; ++i) ((float4*)z)[i] = f4[i];
  const float4* m4 = (const float4*)(mu + (size_t)row * GH2);
  ((float4*)z)[5] = m4[0];
  ((float4*)z)[6] = m4[1];

  float4* zo = (float4*)(z_o + (size_t)row * LAT);
#pragma unroll
  for (int i = 0; i < LAT/4; ++i) zo[i] = ((float4*)z)[i];
  float4* go = (float4*)(gz_o + (size_t)row * GH2);
  go[0] = m4[0]; go[1] = m4[1];

  float q[KCL];
  float ssum = 0.f;
#pragma unroll
  for (int j = 0; j < KCL; ++j) {
    float d = 0.f;
#pragma unroll
    for (int k = 0; k < LAT; ++k) {
      const float df = z[k] - clus[j*LAT + k];
      d = fmaf(df, df, d);
    }
    q[j] = 1.f / (1.f + d);
    ssum += q[j];
  }
  const float inv = 1.f / ssum;
#pragma unroll
  for (int j = 0; j < KCL; ++j) q[j] *= inv;
  float2* qo = (float2*)(q_o + (size_t)row * KCL);
#pragma unroll
  for (int i = 0; i < KCL/2; ++i) qo[i] = ((float2*)q)[i];
}

// ---------------- decoder: 16 rows x 256 cols per block, LDS-staged ----------------
__global__ __launch_bounds__(256) void k_dec(
    const float* __restrict__ z, const float* __restrict__ W, const float* __restrict__ db,
    const float* __restrict__ g3, const float* __restrict__ bb3, float* __restrict__ out)
{
  __shared__ float Ws[LAT][256];   // 28 KB
  __shared__ float zs[16 * LAT];   // 1.75 KB

  const int tid = threadIdx.x;
  const int c0  = blockIdx.x * 256;
  const int r0  = blockIdx.y * 16;

#pragma unroll
  for (int rep = 0; rep < 7; ++rep) {
    const int f4 = rep * 256 + tid;
    const int k  = f4 >> 6;
    const int cg = (f4 & 63) * 4;
    float4 v = make_float4(0.f, 0.f, 0.f, 0.f);
    if (c0 + cg < DIN) v = *(const float4*)&W[(size_t)k * DIN + c0 + cg];
    *(float4*)&Ws[k][cg] = v;
  }
  if (tid < 112) {
    *(float4*)&zs[tid * 4] = *(const float4*)&z[(size_t)r0 * LAT + tid * 4];
  }
  __syncthreads();

  const int w    = tid >> 6;
  const int lane = tid & 63;
  const int cl   = lane * 4;
  const int rloc = w * 4;

  float acc[4][4];
#pragma unroll
  for (int i = 0; i < 4; ++i)
#pragma unroll
    for (int j = 0; j < 4; ++j) acc[i][j] = 0.f;

#pragma unroll
  for (int k4 = 0; k4 < 7; ++k4) {
    float zq[4][4];
#pragma unroll
    for (int i = 0; i < 4; ++i)
      *(float4*)zq[i] = *(const float4*)&zs[(rloc + i) * LAT + k4 * 4];
#pragma unroll
    for (int kk = 0; kk < 4; ++kk) {
      const float4 wv = *(const float4*)&Ws[k4 * 4 + kk][cl];
#pragma unroll
      for (int i = 0; i < 4; ++i) {
        acc[i][0] = fmaf(zq[i][kk], wv.x, acc[i][0]);
        acc[i][1] = fmaf(zq[i][kk], wv.y, acc[i][1]);
        acc[i][2] = fmaf(zq[i][kk], wv.z, acc[i][2]);
        acc[i][3] = fmaf(zq[i][kk], wv.w, acc[i][3]);
      }
    }
  }

  if (c0 + cl >= DIN) return;
  const float4 db4 = *(const float4*)&db[c0 + cl];
  const float4 g4  = *(const float4*)&g3[c0 + cl];
  const float4 bb4 = *(const float4*)&bb3[c0 + cl];
#pragma unroll
  for (int i = 0; i < 4; ++i) {
    float4 v;
    v.x = elu1((acc[i][0] + db4.x) * (g4.x * BN_RS) + bb4.x);
    v.y = elu1((acc[i][1] + db4.y) * (g4.y * BN_RS) + bb4.y);
    v.z = elu1((acc[i][2] + db4.z) * (g4.z * BN_RS) + bb4.z);
    v.w = elu1((acc[i][3] + db4.w) * (g4.w * BN_RS) + bb4.w);
    *(float4*)&out[(size_t)(r0 + rloc + i) * DIN + c0 + cl] = v;
  }
}

extern "C" void kernel_launch(void* const* d_in, const int* in_sizes, int n_in,
                              void* d_out, int out_size, void* d_ws, size_t ws_size,
                              hipStream_t stream) {
  const float* x    = (const float*)d_in[0];
  const float* vals = (const float*)d_in[1];
  const float* W1   = (const float*)d_in[2];
  const float* b1   = (const float*)d_in[3];
  const float* g1   = (const float*)d_in[4];
  const float* bb1  = (const float*)d_in[5];
  const float* W2   = (const float*)d_in[6];
  const float* b2   = (const float*)d_in[7];
  const float* g2   = (const float*)d_in[8];
  const float* bb2  = (const float*)d_in[9];
  const float* gc1W = (const float*)d_in[10];
  const float* gc2W = (const float*)d_in[11];
  const float* gc3W = (const float*)d_in[12];
  const float* dW   = (const float*)d_in[13];
  const float* db   = (const float*)d_in[14];
  const float* g3   = (const float*)d_in[15];
  const float* bb3  = (const float*)d_in[16];
  const float* clus = (const float*)d_in[17];
  const int* erow   = (const int*)d_in[18];
  const int* ecol   = (const int*)d_in[19];

  float* out  = (float*)d_out;
  float* z_o  = out;
  float* mu_o = out + (size_t)NROWS * 28;
  float* lv_o = out + (size_t)NROWS * 36;
  float* de_o = out + (size_t)NROWS * 44;
  float* q_o  = out + (size_t)NROWS * 3044;
  float* fx_o = out + (size_t)NROWS * 3054;
  float* gz_o = out + (size_t)NROWS * 3074;

  // scratch lives inside the de_feat region (written last, fully overwritten)
  float* feat1 = de_o;                                   // [0, 100N)
  float* t1    = de_o + (size_t)NROWS * 100;             // [100N, 132N)
  float* h1    = de_o + (size_t)NROWS * 132;             // [132N, 164N)
  float* mp    = de_o + (size_t)NROWS * 164;             // [164N, 172N)
  float* lp    = de_o + (size_t)NROWS * 172;             // [172N, 180N)
  unsigned short* Wt = (unsigned short*)(de_o + (size_t)NROWS * 200);  // 128x3008 bf16 (rows 112+ never read)
  int*   deg   = (int*)(de_o + (size_t)NROWS * 210);     // [210N, 211N)
  int*   cnt   = (int*)(de_o + (size_t)NROWS * 211);     // [211N, 212N)
  int*   startA= (int*)(de_o + (size_t)NROWS * 212);     // [212N, 214N) (50001 ints)
  int*   colS  = (int*)(de_o + (size_t)NROWS * 214);     // [214N, 230N)
  float* valS  = de_o + (size_t)NROWS * 230;             // [230N, 246N)

  k_prepW<<<dim3(165), 256, 0, stream>>>(W1, Wt);
  k_gemm1<<<dim3(782), 256, 0, stream>>>(x, Wt, b1, g1, bb1, feat1);
  k_enc2_gc1<<<dim3((NROWS + 255) / 256), 256, 0, stream>>>(feat1, W2, b2, g2, bb2, gc1W, fx_o, t1);

  // CSR build (deg & cnt contiguous -> one zero pass)
  k_zero_i<<<dim3(128), 256, 0, stream>>>(deg, 2 * NROWS);
  k_hist<<<dim3((NEDGE + 255) / 256), 256, 0, stream>>>(erow, deg);
  k_scan<<<dim3(1), 1024, 0, stream>>>(deg, startA);
  k_scatter<<<dim3((NEDGE + 255) / 256), 256, 0, stream>>>(erow, ecol, vals, startA, cnt, colS, valS);

  k_spmm1g<<<dim3((NROWS + 31) / 32), 256, 0, stream>>>(startA, colS, valS, t1, h1);
  k_h1gc<<<dim3((NROWS + 255) / 256), 256, 0, stream>>>(h1, gc2W, gc3W, mp, lp);
  k_spmm2g<<<dim3((NROWS + 63) / 64), 256, 0, stream>>>(startA, colS, valS, mp, lp, mu_o, lv_o);
  k_zq<<<dim3((NROWS + 255) / 256), 256, 0, stream>>>(fx_o, mu_o, clus, z_o, gz_o, q_o);
  k_dec<<<dim3(12, 3125), 256, 0, stream>>>(z_o, dW, db, g3, bb3, de_o);
}

// Round 9
// 678.604 us; speedup vs baseline: 1.1004x; 1.1004x over previous
//
#include <hip/hip_runtime.h>
#include <math.h>

#define NROWS 50000
#define DIN   3000
#define FH1   100
#define FH2   20
#define GH1   32
#define GH2   8
#define KCL   10
#define LAT   28
#define NEDGE 800000

static __device__ __forceinline__ float elu1(float v) {
  return v > 0.f ? v : (__expf(v) - 1.f);
}

static __device__ __forceinline__ unsigned short f2bf(float f) {
  unsigned int u = __float_as_uint(f);
  unsigned int r = (u + 0x7FFFu + ((u >> 16) & 1u)) >> 16;
  return (unsigned short)r;
}

#define BN_RS 0.99995000374968754f  /* 1/sqrt(1+1e-4) */

typedef __attribute__((ext_vector_type(8))) short bf16x8_t;
typedef __attribute__((ext_vector_type(4))) float f32x4_t;

// async global->LDS, 16B per lane, dest = wave-uniform base + lane*16
#define GLL(gp, lp)                                                              \
  __builtin_amdgcn_global_load_lds(                                              \
      (const __attribute__((address_space(1))) void*)(gp),                       \
      (__attribute__((address_space(3))) void*)(lp), 16, 0, 0)

// ---------------- prep: Wt[n][k] = bf16(W1[k][n]), n<112 (pad0), k<3008 (pad0) ----------------
__global__ __launch_bounds__(256) void k_prepW(const float* __restrict__ W,
                                               unsigned short* __restrict__ Wt) {
  const int idx = blockIdx.x * 256 + threadIdx.x;   // 112*376 chunks of 8
  const int n = idx / 376;
  const int kc = (idx - n * 376) * 8;
  if (n >= 112) return;
  unsigned short v[8];
#pragma unroll
  for (int j = 0; j < 8; ++j) {
    const int k = kc + j;
    const float f = (n < FH1 && k < DIN) ? W[(size_t)k * FH1 + n] : 0.f;
    v[j] = f2bf(f);
  }
  uint4 pv;
  pv.x = (unsigned)v[0] | ((unsigned)v[1] << 16);
  pv.y = (unsigned)v[2] | ((unsigned)v[3] << 16);
  pv.z = (unsigned)v[4] | ((unsigned)v[5] << 16);
  pv.w = (unsigned)v[6] | ((unsigned)v[7] << 16);
  *(uint4*)&Wt[(size_t)n * 3008 + kc] = pv;
}

// ---------------- prep: Wd[col][k] = bf16(dec_W[k][col]), col<3072 (pad0), k<32 (pad0) ----------
__global__ __launch_bounds__(256) void k_prepDec(const float* __restrict__ W,
                                                 unsigned short* __restrict__ Wd) {
  const int idx = blockIdx.x * 256 + threadIdx.x;   // 3072*4 chunks of 8
  const int col = idx >> 2;
  const int kc = (idx & 3) * 8;
  if (col >= 3072) return;
  unsigned short v[8];
#pragma unroll
  for (int j = 0; j < 8; ++j) {
    const int k = kc + j;
    const float f = (col < DIN && k < LAT) ? W[(size_t)k * DIN + col] : 0.f;
    v[j] = f2bf(f);
  }
  uint4 pv;
  pv.x = (unsigned)v[0] | ((unsigned)v[1] << 16);
  pv.y = (unsigned)v[2] | ((unsigned)v[3] << 16);
  pv.z = (unsigned)v[4] | ((unsigned)v[5] << 16);
  pv.w = (unsigned)v[6] | ((unsigned)v[7] << 16);
  *(uint4*)&Wd[(size_t)col * 32 + kc] = pv;
}

// ---------------- GEMM1 v6 (reverted best): global_load_lds 2-phase double-buffer ----------------
__global__ __launch_bounds__(256) void k_gemm1(
    const float* __restrict__ x, const unsigned short* __restrict__ Wt,
    const float* __restrict__ b1, const float* __restrict__ g1, const float* __restrict__ bb1,
    float* __restrict__ out)
{
  __shared__ float Af[2 * 4096];            // 2 x [64][64] fp32, 16KB each
  __shared__ unsigned short Bf[2 * 7168];   // 2 x [112][64] bf16, 14KB each

  const int tid = threadIdx.x;
  const int w = tid >> 6, lane = tid & 63;
  const int fr = lane & 15;
  const int fk = (lane >> 4) * 8;           // 0,8,16,24
  const int rowBase = blockIdx.x * 64;

  f32x4_t acc[7];
#pragma unroll
  for (int f = 0; f < 7; ++f) acc[f] = (f32x4_t){0.f, 0.f, 0.f, 0.f};

#define STAGE_A(bb, tt)                                                          \
  {                                                                              \
    _Pragma("unroll")                                                            \
    for (int i = 0; i < 4; ++i) {                                                \
      const int c_ = w * 4 + i;                                                  \
      const int rl_ = c_ * 4 + (lane >> 4);                                      \
      const int v_ = lane & 15;                                                  \
      const int u_ = (v_ & 8) | ((v_ ^ rl_) & 7);                                \
      const int rg_ = (rowBase + rl_ < NROWS) ? rowBase + rl_ : (NROWS - 1);     \
      GLL(x + (size_t)rg_ * DIN + (tt) * 64 + u_ * 4,                            \
          (char*)&Af[(bb) * 4096] + c_ * 1024);                                  \
    }                                                                            \
  }
#define STAGE_B(bb, tt)                                                          \
  {                                                                              \
    _Pragma("unroll")                                                            \
    for (int i = 0; i < 4; ++i) {                                                \
      const int c_ = w + i * 4;                                                  \
      if (c_ < 14) {                                                             \
        const int n_ = c_ * 8 + (lane >> 3);                                     \
        const int vb_ = lane & 7;                                                \
        const int ub_ = vb_ ^ (n_ & 7);                                          \
        GLL(Wt + (size_t)n_ * 3008 + (tt) * 64 + ub_ * 8,                        \
            (char*)&Bf[(bb) * 7168] + c_ * 1024);                                \
      }                                                                          \
    }                                                                            \
  }
#define STAGE_A_TAIL(bb)                                                         \
  {                                                                              \
    _Pragma("unroll")                                                            \
    for (int j = 0; j < 4; ++j) {                                                \
      const int idx_ = tid * 4 + j;                                              \
      const int r_ = idx_ >> 4;                                                  \
      const int u_ = idx_ & 15;                                                  \
      const int kk_ = 2944 + u_ * 4;                                             \
      const int rg_ = (rowBase + r_ < NROWS) ? rowBase + r_ : (NROWS - 1);       \
      float4 val_ = make_float4(0.f, 0.f, 0.f, 0.f);                             \
      if (kk_ + 3 < DIN) val_ = *(const float4*)&x[(size_t)rg_ * DIN + kk_];     \
      const int v_ = (u_ & 8) | ((u_ ^ r_) & 7);                                 \
      *(float4*)&Af[(bb) * 4096 + r_ * 64 + v_ * 4] = val_;                      \
    }                                                                            \
  }

  STAGE_A(0, 0)
  STAGE_B(0, 0)
  __syncthreads();

  const int r = w * 16 + fr;
  int cur = 0;

  for (int t = 0; t < 47; ++t) {
    if (t < 46) {
      if (t + 1 == 46) { STAGE_A_TAIL(cur ^ 1) } else { STAGE_A(cur ^ 1, t + 1) }
      STAGE_B(cur ^ 1, t + 1)
    }

    const float* Ab = &Af[cur * 4096 + r * 64];
    bf16x8_t a[2];
#pragma unroll
    for (int h = 0; h < 2; ++h) {
      const int u0 = h * 8 + (fk >> 2);
      const int u1 = u0 + 1;
      const int v0 = (u0 & 8) | ((u0 ^ r) & 7);
      const int v1 = (u1 & 8) | ((u1 ^ r) & 7);
      const float4 p = *(const float4*)&Ab[v0 * 4];
      const float4 q = *(const float4*)&Ab[v1 * 4];
      uint4 av;
      av.x = (unsigned)f2bf(p.x) | ((unsigned)f2bf(p.y) << 16);
      av.y = (unsigned)f2bf(p.z) | ((unsigned)f2bf(p.w) << 16);
      av.z = (unsigned)f2bf(q.x) | ((unsigned)f2bf(q.y) << 16);
      av.w = (unsigned)f2bf(q.z) | ((unsigned)f2bf(q.w) << 16);
      a[h] = *(const bf16x8_t*)&av;
    }
#pragma unroll
    for (int f = 0; f < 7; ++f) {
      const int n = f * 16 + fr;
      const int ub0 = (fk >> 3);
#pragma unroll
      for (int h = 0; h < 2; ++h) {
        const int vb = (h * 4 + ub0) ^ (n & 7);
        const bf16x8_t b = *(const bf16x8_t*)&Bf[cur * 7168 + n * 64 + vb * 8];
        acc[f] = __builtin_amdgcn_mfma_f32_16x16x32_bf16(a[h], b, acc[f], 0, 0, 0);
      }
    }

    __syncthreads();
    cur ^= 1;
  }
#undef STAGE_A
#undef STAGE_B
#undef STAGE_A_TAIL

  const int s4 = (lane >> 4) * 4;
#pragma unroll
  for (int f = 0; f < 7; ++f) {
    const int col = f * 16 + fr;
    if (col < FH1) {
      const float sc = g1[col] * BN_RS;
      const float bbv = bb1[col];
      const float bv = b1[col];
#pragma unroll
      for (int j = 0; j < 4; ++j) {
        const int row = rowBase + w * 16 + s4 + j;
        if (row < NROWS)
          out[(size_t)row * FH1 + col] = elu1((acc[f][j] + bv) * sc + bbv);
      }
    }
  }
}

// ---------------- feat_x = ELU(BN(feat1 @ W2 + b2)); t1 = feat_x @ gc1_W ----------------
__global__ __launch_bounds__(256) void k_enc2_gc1(
    const float* __restrict__ feat1, const float* __restrict__ W2, const float* __restrict__ b2,
    const float* __restrict__ g2, const float* __restrict__ bb2,
    const float* __restrict__ gc1W,
    float* __restrict__ fx_out, float* __restrict__ t1_out)
{
  const int row = blockIdx.x * blockDim.x + threadIdx.x;
  if (row >= NROWS) return;
  float f1[FH1];
  const float4* fr = (const float4*)(feat1 + (size_t)row * FH1);
#pragma unroll
  for (int i = 0; i < FH1/4; ++i) ((float4*)f1)[i] = fr[i];

  float fx[FH2];
#pragma unroll
  for (int j = 0; j < FH2; ++j) fx[j] = b2[j];
#pragma unroll
  for (int k = 0; k < FH1; ++k) {
    const float f = f1[k];
#pragma unroll
    for (int j = 0; j < FH2; ++j) fx[j] = fmaf(f, W2[k*FH2 + j], fx[j]);
  }
#pragma unroll
  for (int j = 0; j < FH2; ++j) fx[j] = elu1(fx[j] * (g2[j] * BN_RS) + bb2[j]);

  float4* fo = (float4*)(fx_out + (size_t)row * FH2);
#pragma unroll
  for (int i = 0; i < FH2/4; ++i) fo[i] = ((float4*)fx)[i];

  float t[GH1];
#pragma unroll
  for (int j = 0; j < GH1; ++j) t[j] = 0.f;
#pragma unroll
  for (int k = 0; k < FH2; ++k) {
    const float f = fx[k];
#pragma unroll
    for (int j = 0; j < GH1; ++j) t[j] = fmaf(f, gc1W[k*GH1 + j], t[j]);
  }
  float4* to = (float4*)(t1_out + (size_t)row * GH1);
#pragma unroll
  for (int i = 0; i < GH1/4; ++i) to[i] = ((float4*)t)[i];
}

// ---------------- CSR build: zero -> hist -> scan -> scatter ----------------
__global__ void k_zero_i(int* __restrict__ p, int n) {
  for (int i = blockIdx.x * blockDim.x + threadIdx.x; i < n; i += gridDim.x * blockDim.x)
    p[i] = 0;
}

__global__ void k_hist(const int* __restrict__ er, int* __restrict__ deg) {
  const int e = blockIdx.x * 256 + threadIdx.x;
  if (e < NEDGE) atomicAdd(&deg[er[e]], 1);
}

__global__ __launch_bounds__(1024) void k_scan(const int* __restrict__ deg,
                                               int* __restrict__ start) {
  __shared__ int sm[1024];
  const int t = threadIdx.x;
  const int c0 = t * 49;
  const int c1 = (c0 + 49 < NROWS) ? c0 + 49 : NROWS;
  int s = 0;
  for (int i = c0; i < c1; ++i) s += deg[i];
  sm[t] = s;
  __syncthreads();
  for (int off = 1; off < 1024; off <<= 1) {
    int v = (t >= off) ? sm[t - off] : 0;
    __syncthreads();
    sm[t] += v;
    __syncthreads();
  }
  int run = (t == 0) ? 0 : sm[t - 1];
  for (int i = c0; i < c1; ++i) { start[i] = run; run += deg[i]; }
  if (t == 0) start[NROWS] = NEDGE;
}

__global__ void k_scatter(const int* __restrict__ er, const int* __restrict__ ec,
                          const float* __restrict__ vals, const int* __restrict__ start,
                          int* __restrict__ cnt, int* __restrict__ colS,
                          float* __restrict__ valS) {
  const int e = blockIdx.x * 256 + threadIdx.x;
  if (e >= NEDGE) return;
  const int r = er[e];
  const int pos = start[r] + atomicAdd(&cnt[r], 1);
  colS[pos] = ec[e];
  valS[pos] = vals[e];
}

// ---------------- spmm1 gather: h1[r] = sum_j val*t1[col], 8 thr/row ----------------
__global__ __launch_bounds__(256) void k_spmm1g(
    const int* __restrict__ start, const int* __restrict__ colS, const float* __restrict__ valS,
    const float* __restrict__ t1, float* __restrict__ h1)
{
  const int tid = threadIdx.x;
  const int row = blockIdx.x * 32 + (tid >> 3);
  const int p = tid & 7;
  if (row >= NROWS) return;
  const int s = start[row], e = start[row + 1];
  float4 acc = make_float4(0.f, 0.f, 0.f, 0.f);
  for (int j = s; j < e; ++j) {
    const int c = colS[j];
    const float v = valS[j];
    const float4 tv = *(const float4*)&t1[(size_t)c * GH1 + p * 4];
    acc.x = fmaf(v, tv.x, acc.x);
    acc.y = fmaf(v, tv.y, acc.y);
    acc.z = fmaf(v, tv.z, acc.z);
    acc.w = fmaf(v, tv.w, acc.w);
  }
  *(float4*)&h1[(size_t)row * GH1 + p * 4] = acc;
}

// ---------------- mu_pre/lv_pre = relu(h1) @ gc2W / gc3W ----------------
__global__ __launch_bounds__(256) void k_h1gc(
    const float* __restrict__ h1, const float* __restrict__ gc2W, const float* __restrict__ gc3W,
    float* __restrict__ mp, float* __restrict__ lp)
{
  const int row = blockIdx.x * blockDim.x + threadIdx.x;
  if (row >= NROWS) return;
  float h[GH1];
  const float4* hr = (const float4*)(h1 + (size_t)row * GH1);
#pragma unroll
  for (int i = 0; i < GH1/4; ++i) ((float4*)h)[i] = hr[i];
#pragma unroll
  for (int k = 0; k < GH1; ++k) h[k] = fmaxf(h[k], 0.f);

  float m[GH2], l[GH2];
#pragma unroll
  for (int j = 0; j < GH2; ++j) { m[j] = 0.f; l[j] = 0.f; }
#pragma unroll
  for (int k = 0; k < GH1; ++k) {
    const float hv = h[k];
#pragma unroll
    for (int j = 0; j < GH2; ++j) {
      m[j] = fmaf(hv, gc2W[k*GH2 + j], m[j]);
      l[j] = fmaf(hv, gc3W[k*GH2 + j], l[j]);
    }
  }
  float4* mo = (float4*)(mp + (size_t)row * GH2);
  float4* lo = (float4*)(lp + (size_t)row * GH2);
  mo[0] = ((float4*)m)[0]; mo[1] = ((float4*)m)[1];
  lo[0] = ((float4*)l)[0]; lo[1] = ((float4*)l)[1];
}

// ---------------- spmm2 gather: mu/lv, 4 thr/row ----------------
__global__ __launch_bounds__(256) void k_spmm2g(
    const int* __restrict__ start, const int* __restrict__ colS, const float* __restrict__ valS,
    const float* __restrict__ mp, const float* __restrict__ lp,
    float* __restrict__ mu, float* __restrict__ lv)
{
  const int tid = threadIdx.x;
  const int row = blockIdx.x * 64 + (tid >> 2);
  const int p = tid & 3;
  if (row >= NROWS) return;
  const float* src = (p < 2) ? mp : lp;
  float* dst = (p < 2) ? mu : lv;
  const int off = (p & 1) * 4;
  const int s = start[row], e = start[row + 1];
  float4 acc = make_float4(0.f, 0.f, 0.f, 0.f);
  for (int j = s; j < e; ++j) {
    const int c = colS[j];
    const float v = valS[j];
    const float4 sv = *(const float4*)&src[(size_t)c * GH2 + off];
    acc.x = fmaf(v, sv.x, acc.x);
    acc.y = fmaf(v, sv.y, acc.y);
    acc.z = fmaf(v, sv.z, acc.z);
    acc.w = fmaf(v, sv.w, acc.w);
  }
  *(float4*)&dst[(size_t)row * GH2 + off] = acc;
}

// ---------------- z = [feat_x | mu]; gnn_z = mu; q = student-t ----------------
__global__ __launch_bounds__(256) void k_zq(
    const float* __restrict__ fx, const float* __restrict__ mu, const float* __restrict__ clus,
    float* __restrict__ z_o, float* __restrict__ gz_o, float* __restrict__ q_o)
{
  const int row = blockIdx.x * blockDim.x + threadIdx.x;
  if (row >= NROWS) return;
  float z[LAT];
  const float4* f4 = (const float4*)(fx + (size_t)row * FH2);
#pragma unroll
  for (int i = 0; i < FH2/4; ++i) ((float4*)z)[i] = f4[i];
  const float4* m4 = (const float4*)(mu + (size_t)row * GH2);
  ((float4*)z)[5] = m4[0];
  ((float4*)z)[6] = m4[1];

  float4* zo = (float4*)(z_o + (size_t)row * LAT);
#pragma unroll
  for (int i = 0; i < LAT/4; ++i) zo[i] = ((float4*)z)[i];
  float4* go = (float4*)(gz_o + (size_t)row * GH2);
  go[0] = m4[0]; go[1] = m4[1];

  float q[KCL];
  float ssum = 0.f;
#pragma unroll
  for (int j = 0; j < KCL; ++j) {
    float d = 0.f;
#pragma unroll
    for (int k = 0; k < LAT; ++k) {
      const float df = z[k] - clus[j*LAT + k];
      d = fmaf(df, df, d);
    }
    q[j] = 1.f / (1.f + d);
    ssum += q[j];
  }
  const float inv = 1.f / ssum;
#pragma unroll
  for (int j = 0; j < KCL; ++j) q[j] *= inv;
  float2* qo = (float2*)(q_o + (size_t)row * KCL);
#pragma unroll
  for (int i = 0; i < KCL/2; ++i) qo[i] = ((float2*)q)[i];
}

// ---------------- decoder main (MFMA, LDS-free): skips y=213,214 (Wd rows) ----------------
// Per wave: 16 rows x 64 cols. A-frag direct from z (L2), B-frags direct from Wd (L2).
__global__ __launch_bounds__(256) void k_decm(
    const float* __restrict__ z, const unsigned short* __restrict__ Wd,
    const float* __restrict__ db, const float* __restrict__ g3, const float* __restrict__ bb3,
    float* __restrict__ out)
{
  const int yb = blockIdx.y;
  if (yb == 213 || yb == 214) return;   // Wd lives in these output rows; fp32 tail covers them
  const int tid = threadIdx.x;
  const int w = tid >> 6, lane = tid & 63;
  const int fr = lane & 15;
  const int g = lane >> 4;
  const int fk = g * 8;
  const int r0 = yb * 16;
  const int c0w = blockIdx.x * 256 + w * 64;

  // A-frag: z[r0+fr][fk..fk+7]; k>=28 -> 0
  const float* zp = z + (size_t)(r0 + fr) * LAT;
  float4 p = make_float4(0.f, 0.f, 0.f, 0.f), q = p;
  if (g < 3) {
    p = *(const float4*)&zp[fk];
    q = *(const float4*)&zp[fk + 4];
  } else {
    p = *(const float4*)&zp[24];
  }
  uint4 av;
  av.x = (unsigned)f2bf(p.x) | ((unsigned)f2bf(p.y) << 16);
  av.y = (unsigned)f2bf(p.z) | ((unsigned)f2bf(p.w) << 16);
  av.z = (unsigned)f2bf(q.x) | ((unsigned)f2bf(q.y) << 16);
  av.w = (unsigned)f2bf(q.z) | ((unsigned)f2bf(q.w) << 16);
  const bf16x8_t a = *(const bf16x8_t*)&av;

#pragma unroll
  for (int nf = 0; nf < 4; ++nf) {
    const int col = c0w + nf * 16 + fr;
    const uint4 bv = *(const uint4*)&Wd[(size_t)col * 32 + fk];
    f32x4_t acc = (f32x4_t){0.f, 0.f, 0.f, 0.f};
    acc = __builtin_amdgcn_mfma_f32_16x16x32_bf16(a, *(const bf16x8_t*)&bv, acc, 0, 0, 0);
    if (col < DIN) {
      const float sc = g3[col] * BN_RS;
      const float bbv = bb3[col];
      const float dbv = db[col];
#pragma unroll
      for (int j = 0; j < 4; ++j) {
        const int row = r0 + g * 4 + j;
        out[(size_t)row * DIN + col] = elu1((acc[j] + dbv) * sc + bbv);
      }
    }
  }
}

// ---------------- decoder tail (fp32, rows 3408-3439): runs AFTER k_decm ----------------
__global__ __launch_bounds__(256) void k_dect(
    const float* __restrict__ z, const float* __restrict__ W, const float* __restrict__ db,
    const float* __restrict__ g3, const float* __restrict__ bb3, float* __restrict__ out)
{
  __shared__ float Ws[LAT][256];
  __shared__ float zs[16 * LAT];

  const int tid = threadIdx.x;
  const int c0  = blockIdx.x * 256;
  const int r0  = (blockIdx.y + 213) * 16;

#pragma unroll
  for (int rep = 0; rep < 7; ++rep) {
    const int f4 = rep * 256 + tid;
    const int k  = f4 >> 6;
    const int cg = (f4 & 63) * 4;
    float4 v = make_float4(0.f, 0.f, 0.f, 0.f);
    if (c0 + cg < DIN) v = *(const float4*)&W[(size_t)k * DIN + c0 + cg];
    *(float4*)&Ws[k][cg] = v;
  }
  if (tid < 112) {
    *(float4*)&zs[tid * 4] = *(const float4*)&z[(size_t)r0 * LAT + tid * 4];
  }
  __syncthreads();

  const int w    = tid >> 6;
  const int lane = tid & 63;
  const int cl   = lane * 4;
  const int rloc = w * 4;

  float acc[4][4];
#pragma unroll
  for (int i = 0; i < 4; ++i)
#pragma unroll
    for (int j = 0; j < 4; ++j) acc[i][j] = 0.f;

#pragma unroll
  for (int k4 = 0; k4 < 7; ++k4) {
    float zq[4][4];
#pragma unroll
    for (int i = 0; i < 4; ++i)
      *(float4*)zq[i] = *(const float4*)&zs[(rloc + i) * LAT + k4 * 4];
#pragma unroll
    for (int kk = 0; kk < 4; ++kk) {
      const float4 wv = *(const float4*)&Ws[k4 * 4 + kk][cl];
#pragma unroll
      for (int i = 0; i < 4; ++i) {
        acc[i][0] = fmaf(zq[i][kk], wv.x, acc[i][0]);
        acc[i][1] = fmaf(zq[i][kk], wv.y, acc[i][1]);
        acc[i][2] = fmaf(zq[i][kk], wv.z, acc[i][2]);
        acc[i][3] = fmaf(zq[i][kk], wv.w, acc[i][3]);
      }
    }
  }

  if (c0 + cl >= DIN) return;
  const float4 db4 = *(const float4*)&db[c0 + cl];
  const float4 g4  = *(const float4*)&g3[c0 + cl];
  const float4 bb4 = *(const float4*)&bb3[c0 + cl];
#pragma unroll
  for (int i = 0; i < 4; ++i) {
    float4 v;
    v.x = elu1((acc[i][0] + db4.x) * (g4.x * BN_RS) + bb4.x);
    v.y = elu1((acc[i][1] + db4.y) * (g4.y * BN_RS) + bb4.y);
    v.z = elu1((acc[i][2] + db4.z) * (g4.z * BN_RS) + bb4.z);
    v.w = elu1((acc[i][3] + db4.w) * (g4.w * BN_RS) + bb4.w);
    *(float4*)&out[(size_t)(r0 + rloc + i) * DIN + c0 + cl] = v;
  }
}

extern "C" void kernel_launch(void* const* d_in, const int* in_sizes, int n_in,
                              void* d_out, int out_size, void* d_ws, size_t ws_size,
                              hipStream_t stream) {
  const float* x    = (const float*)d_in[0];
  const float* vals = (const float*)d_in[1];
  const float* W1   = (const float*)d_in[2];
  const float* b1   = (const float*)d_in[3];
  const float* g1   = (const float*)d_in[4];
  const float* bb1  = (const float*)d_in[5];
  const float* W2   = (const float*)d_in[6];
  const float* b2   = (const float*)d_in[7];
  const float* g2   = (const float*)d_in[8];
  const float* bb2  = (const float*)d_in[9];
  const float* gc1W = (const float*)d_in[10];
  const float* gc2W = (const float*)d_in[11];
  const float* gc3W = (const float*)d_in[12];
  const float* dW   = (const float*)d_in[13];
  const float* db   = (const float*)d_in[14];
  const float* g3   = (const float*)d_in[15];
  const float* bb3  = (const float*)d_in[16];
  const float* clus = (const float*)d_in[17];
  const int* erow   = (const int*)d_in[18];
  const int* ecol   = (const int*)d_in[19];

  float* out  = (float*)d_out;
  float* z_o  = out;
  float* mu_o = out + (size_t)NROWS * 28;
  float* lv_o = out + (size_t)NROWS * 36;
  float* de_o = out + (size_t)NROWS * 44;
  float* q_o  = out + (size_t)NROWS * 3044;
  float* fx_o = out + (size_t)NROWS * 3054;
  float* gz_o = out + (size_t)NROWS * 3074;

  // scratch inside de_feat region (dead before the writer reaches it):
  float* feat1 = de_o;                                   // rows 0..
  float* t1    = de_o + (size_t)NROWS * 100;
  float* h1    = de_o + (size_t)NROWS * 132;
  float* mp    = de_o + (size_t)NROWS * 164;
  float* lp    = de_o + (size_t)NROWS * 172;
  unsigned short* Wt = (unsigned short*)(de_o + (size_t)NROWS * 200);      // rows ~3333-3390
  unsigned short* Wd = (unsigned short*)(de_o + (size_t)3408 * DIN);       // rows 3408-3424 (y 213/214)
  int*   deg   = (int*)(de_o + (size_t)NROWS * 210);     // rows 3500+
  int*   cnt   = (int*)(de_o + (size_t)NROWS * 211);
  int*   startA= (int*)(de_o + (size_t)NROWS * 212);
  int*   colS  = (int*)(de_o + (size_t)NROWS * 214);
  float* valS  = de_o + (size_t)NROWS * 230;

  k_prepW<<<dim3(165), 256, 0, stream>>>(W1, Wt);
  k_prepDec<<<dim3(48), 256, 0, stream>>>(dW, Wd);
  k_gemm1<<<dim3(782), 256, 0, stream>>>(x, Wt, b1, g1, bb1, feat1);
  k_enc2_gc1<<<dim3((NROWS + 255) / 256), 256, 0, stream>>>(feat1, W2, b2, g2, bb2, gc1W, fx_o, t1);

  k_zero_i<<<dim3(128), 256, 0, stream>>>(deg, 2 * NROWS);
  k_hist<<<dim3((NEDGE + 255) / 256), 256, 0, stream>>>(erow, deg);
  k_scan<<<dim3(1), 1024, 0, stream>>>(deg, startA);
  k_scatter<<<dim3((NEDGE + 255) / 256), 256, 0, stream>>>(erow, ecol, vals, startA, cnt, colS, valS);

  k_spmm1g<<<dim3((NROWS + 31) / 32), 256, 0, stream>>>(startA, colS, valS, t1, h1);
  k_h1gc<<<dim3((NROWS + 255) / 256), 256, 0, stream>>>(h1, gc2W, gc3W, mp, lp);
  k_spmm2g<<<dim3((NROWS + 63) / 64), 256, 0, stream>>>(startA, colS, valS, mp, lp, mu_o, lv_o);
  k_zq<<<dim3((NROWS + 255) / 256), 256, 0, stream>>>(fx_o, mu_o, clus, z_o, gz_o, q_o);
  k_decm<<<dim3(12, 3125), 256, 0, stream>>>(z_o, Wd, db, g3, bb3, de_o);
  k_dect<<<dim3(12, 2), 256, 0, stream>>>(z_o, dW, db, g3, bb3, de_o);   // rows 3408-3439, after k_decm
}

// Round 10
// 653.750 us; speedup vs baseline: 1.1423x; 1.0380x over previous
//
#include <hip/hip_runtime.h>
#include <math.h>

#define NROWS 50000
#define DIN   3000
#define FH1   100
#define FH2   20
#define GH1   32
#define GH2   8
#define KCL   10
#define LAT   28
#define NEDGE 800000

static __device__ __forceinline__ float elu1(float v) {
  return v > 0.f ? v : (__expf(v) - 1.f);
}

static __device__ __forceinline__ unsigned short f2bf(float f) {
  unsigned int u = __float_as_uint(f);
  unsigned int r = (u + 0x7FFFu + ((u >> 16) & 1u)) >> 16;
  return (unsigned short)r;
}

#define BN_RS 0.99995000374968754f  /* 1/sqrt(1+1e-4) */

typedef __attribute__((ext_vector_type(8))) short bf16x8_t;
typedef __attribute__((ext_vector_type(4))) float f32x4_t;

// async global->LDS, 16B per lane, dest = wave-uniform base + lane*16
#define GLL(gp, lp)                                                              \
  __builtin_amdgcn_global_load_lds(                                              \
      (const __attribute__((address_space(1))) void*)(gp),                       \
      (__attribute__((address_space(3))) void*)(lp), 16, 0, 0)

// ---------------- prep: Wt[n][k] = bf16(W1[k][n]), n<112 (pad0), k<3008 (pad0) ----------------
__global__ __launch_bounds__(256) void k_prepW(const float* __restrict__ W,
                                               unsigned short* __restrict__ Wt) {
  const int idx = blockIdx.x * 256 + threadIdx.x;   // 112*376 chunks of 8
  const int n = idx / 376;
  const int kc = (idx - n * 376) * 8;
  if (n >= 112) return;
  unsigned short v[8];
#pragma unroll
  for (int j = 0; j < 8; ++j) {
    const int k = kc + j;
    const float f = (n < FH1 && k < DIN) ? W[(size_t)k * FH1 + n] : 0.f;
    v[j] = f2bf(f);
  }
  uint4 pv;
  pv.x = (unsigned)v[0] | ((unsigned)v[1] << 16);
  pv.y = (unsigned)v[2] | ((unsigned)v[3] << 16);
  pv.z = (unsigned)v[4] | ((unsigned)v[5] << 16);
  pv.w = (unsigned)v[6] | ((unsigned)v[7] << 16);
  *(uint4*)&Wt[(size_t)n * 3008 + kc] = pv;
}

// ---------------- GEMM1 v8: v6 geometry + uniform loads + counted vmcnt(8) ----------------
// BK=64, 2 buffers: A fp32 [64][64] 16KB + B bf16 [128][64] 16KB (rows 112-127 staged,
// never consumed) = 32KB/buf x2 = 64KB -> 2 blocks/CU. Every wave issues exactly
// 4 A + 4 B global_load_lds per tile -> per-iter wait = vmcnt(8): tile t landed,
// tile t+1 still in flight. Raw barriers (no drain). Tail tile 46: A source offset
// clamps to 2996; garbage k>=3000 lanes multiply zero-padded B columns.
__global__ __launch_bounds__(256) void k_gemm1(
    const float* __restrict__ x, const unsigned short* __restrict__ Wt,
    const float* __restrict__ b1, const float* __restrict__ g1, const float* __restrict__ bb1,
    float* __restrict__ out)
{
  __shared__ float Af[2 * 4096];            // 2 x [64][64] fp32, 16KB each
  __shared__ unsigned short Bf[2 * 8192];   // 2 x [128][64] bf16, 16KB each

  const int tid = threadIdx.x;
  const int w = tid >> 6, lane = tid & 63;
  const int fr = lane & 15;
  const int fk = (lane >> 4) * 8;           // 0,8,16,24
  const int rowBase = blockIdx.x * 64;

  f32x4_t acc[7];
#pragma unroll
  for (int f = 0; f < 7; ++f) acc[f] = (f32x4_t){0.f, 0.f, 0.f, 0.f};

  // uniform staging: 4 A-chunks + 4 B-chunks of 1KB per wave per tile (8 GLL)
#define STAGE(bb, tt)                                                            \
  {                                                                              \
    _Pragma("unroll")                                                            \
    for (int i = 0; i < 4; ++i) {                                                \
      const int c_ = w * 4 + i;                                                  \
      const int rl_ = c_ * 4 + (lane >> 4);                                      \
      const int v_ = lane & 15;                                                  \
      const int u_ = (v_ & 8) | ((v_ ^ rl_) & 7);                                \
      const int rg_ = (rowBase + rl_ < NROWS) ? rowBase + rl_ : (NROWS - 1);     \
      int ko_ = (tt) * 64 + u_ * 4;                                              \
      if (ko_ > 2996) ko_ = 2996;  /* tail: garbage lanes multiply B=0 */        \
      GLL(x + (size_t)rg_ * DIN + ko_, (char*)&Af[(bb) * 4096] + c_ * 1024);     \
    }                                                                            \
    _Pragma("unroll")                                                            \
    for (int i = 0; i < 4; ++i) {                                                \
      const int c_ = w + i * 4;                                                  \
      const int n_ = c_ * 8 + (lane >> 3);                                       \
      const int ub_ = (lane & 7) ^ (n_ & 7);                                     \
      GLL(Wt + (size_t)n_ * 3008 + (tt) * 64 + ub_ * 8,                          \
          (char*)&Bf[(bb) * 8192] + c_ * 1024);                                  \
    }                                                                            \
  }

#define COMPUTE(bb)                                                              \
  {                                                                              \
    const int r_ = w * 16 + fr;                                                  \
    const float* Ab_ = &Af[(bb) * 4096 + r_ * 64];                               \
    bf16x8_t a_[2];                                                              \
    _Pragma("unroll")                                                            \
    for (int h = 0; h < 2; ++h) {                                                \
      const int u0_ = h * 8 + (fk >> 2);                                         \
      const int u1_ = u0_ + 1;                                                   \
      const int v0_ = (u0_ & 8) | ((u0_ ^ r_) & 7);                              \
      const int v1_ = (u1_ & 8) | ((u1_ ^ r_) & 7);                              \
      const float4 p_ = *(const float4*)&Ab_[v0_ * 4];                           \
      const float4 q_ = *(const float4*)&Ab_[v1_ * 4];                           \
      uint4 av_;                                                                 \
      av_.x = (unsigned)f2bf(p_.x) | ((unsigned)f2bf(p_.y) << 16);               \
      av_.y = (unsigned)f2bf(p_.z) | ((unsigned)f2bf(p_.w) << 16);               \
      av_.z = (unsigned)f2bf(q_.x) | ((unsigned)f2bf(q_.y) << 16);               \
      av_.w = (unsigned)f2bf(q_.z) | ((unsigned)f2bf(q_.w) << 16);               \
      a_[h] = *(const bf16x8_t*)&av_;                                            \
    }                                                                            \
    _Pragma("unroll")                                                            \
    for (int f = 0; f < 7; ++f) {                                                \
      const int n_ = f * 16 + fr;                                                \
      const int ub0_ = (fk >> 3);                                                \
      _Pragma("unroll")                                                          \
      for (int h = 0; h < 2; ++h) {                                              \
        const int vb_ = (h * 4 + ub0_) ^ (n_ & 7);                               \
        const bf16x8_t b_ = *(const bf16x8_t*)&Bf[(bb) * 8192 + n_ * 64 + vb_ * 8]; \
        acc[f] = __builtin_amdgcn_mfma_f32_16x16x32_bf16(a_[h], b_, acc[f], 0, 0, 0); \
      }                                                                          \
    }                                                                            \
  }

  STAGE(0, 0)
  STAGE(1, 1)

  for (int t = 0; t < 46; ++t) {
    asm volatile("s_waitcnt vmcnt(8)" ::: "memory");   // tile t landed; t+1 in flight
    __builtin_amdgcn_s_barrier();
    __builtin_amdgcn_sched_barrier(0);
    COMPUTE(t & 1)
    __builtin_amdgcn_sched_barrier(0);
    __builtin_amdgcn_s_barrier();                      // all waves done reading buf t&1
    __builtin_amdgcn_sched_barrier(0);
    if (t < 45) STAGE(t & 1, t + 2)
  }
  asm volatile("s_waitcnt vmcnt(0)" ::: "memory");     // tile 46 landed
  __builtin_amdgcn_s_barrier();
  __builtin_amdgcn_sched_barrier(0);
  COMPUTE(0)
#undef STAGE
#undef COMPUTE

  // epilogue: C/D layout col=lane&15, row=(lane>>4)*4+reg
  const int s4 = (lane >> 4) * 4;
#pragma unroll
  for (int f = 0; f < 7; ++f) {
    const int col = f * 16 + fr;
    if (col < FH1) {
      const float sc = g1[col] * BN_RS;
      const float bbv = bb1[col];
      const float bv = b1[col];
#pragma unroll
      for (int j = 0; j < 4; ++j) {
        const int row = rowBase + w * 16 + s4 + j;
        if (row < NROWS)
          out[(size_t)row * FH1 + col] = elu1((acc[f][j] + bv) * sc + bbv);
      }
    }
  }
}

// ---------------- feat_x = ELU(BN(feat1 @ W2 + b2)); t1 = feat_x @ gc1_W ----------------
__global__ __launch_bounds__(256) void k_enc2_gc1(
    const float* __restrict__ feat1, const float* __restrict__ W2, const float* __restrict__ b2,
    const float* __restrict__ g2, const float* __restrict__ bb2,
    const float* __restrict__ gc1W,
    float* __restrict__ fx_out, float* __restrict__ t1_out)
{
  const int row = blockIdx.x * blockDim.x + threadIdx.x;
  if (row >= NROWS) return;
  float f1[FH1];
  const float4* fr = (const float4*)(feat1 + (size_t)row * FH1);
#pragma unroll
  for (int i = 0; i < FH1/4; ++i) ((float4*)f1)[i] = fr[i];

  float fx[FH2];
#pragma unroll
  for (int j = 0; j < FH2; ++j) fx[j] = b2[j];
#pragma unroll
  for (int k = 0; k < FH1; ++k) {
    const float f = f1[k];
#pragma unroll
    for (int j = 0; j < FH2; ++j) fx[j] = fmaf(f, W2[k*FH2 + j], fx[j]);
  }
#pragma unroll
  for (int j = 0; j < FH2; ++j) fx[j] = elu1(fx[j] * (g2[j] * BN_RS) + bb2[j]);

  float4* fo = (float4*)(fx_out + (size_t)row * FH2);
#pragma unroll
  for (int i = 0; i < FH2/4; ++i) fo[i] = ((float4*)fx)[i];

  float t[GH1];
#pragma unroll
  for (int j = 0; j < GH1; ++j) t[j] = 0.f;
#pragma unroll
  for (int k = 0; k < FH2; ++k) {
    const float f = fx[k];
#pragma unroll
    for (int j = 0; j < GH1; ++j) t[j] = fmaf(f, gc1W[k*GH1 + j], t[j]);
  }
  float4* to = (float4*)(t1_out + (size_t)row * GH1);
#pragma unroll
  for (int i = 0; i < GH1/4; ++i) to[i] = ((float4*)t)[i];
}

// ---------------- CSR build: zero -> hist -> scan -> scatter ----------------
__global__ void k_zero_i(int* __restrict__ p, int n) {
  for (int i = blockIdx.x * blockDim.x + threadIdx.x; i < n; i += gridDim.x * blockDim.x)
    p[i] = 0;
}

__global__ void k_hist(const int* __restrict__ er, int* __restrict__ deg) {
  const int e = blockIdx.x * 256 + threadIdx.x;
  if (e < NEDGE) atomicAdd(&deg[er[e]], 1);
}

__global__ __launch_bounds__(1024) void k_scan(const int* __restrict__ deg,
                                               int* __restrict__ start) {
  __shared__ int sm[1024];
  const int t = threadIdx.x;
  const int c0 = t * 49;
  const int c1 = (c0 + 49 < NROWS) ? c0 + 49 : NROWS;
  int s = 0;
  for (int i = c0; i < c1; ++i) s += deg[i];
  sm[t] = s;
  __syncthreads();
  for (int off = 1; off < 1024; off <<= 1) {
    int v = (t >= off) ? sm[t - off] : 0;
    __syncthreads();
    sm[t] += v;
    __syncthreads();
  }
  int run = (t == 0) ? 0 : sm[t - 1];
  for (int i = c0; i < c1; ++i) { start[i] = run; run += deg[i]; }
  if (t == 0) start[NROWS] = NEDGE;
}

__global__ void k_scatter(const int* __restrict__ er, const int* __restrict__ ec,
                          const float* __restrict__ vals, const int* __restrict__ start,
                          int* __restrict__ cnt, int* __restrict__ colS,
                          float* __restrict__ valS) {
  const int e = blockIdx.x * 256 + threadIdx.x;
  if (e >= NEDGE) return;
  const int r = er[e];
  const int pos = start[r] + atomicAdd(&cnt[r], 1);
  colS[pos] = ec[e];
  valS[pos] = vals[e];
}

// ---------------- spmm1 gather: h1[r] = sum_j val*t1[col], 8 thr/row ----------------
__global__ __launch_bounds__(256) void k_spmm1g(
    const int* __restrict__ start, const int* __restrict__ colS, const float* __restrict__ valS,
    const float* __restrict__ t1, float* __restrict__ h1)
{
  const int tid = threadIdx.x;
  const int row = blockIdx.x * 32 + (tid >> 3);
  const int p = tid & 7;
  if (row >= NROWS) return;
  const int s = start[row], e = start[row + 1];
  float4 acc = make_float4(0.f, 0.f, 0.f, 0.f);
  for (int j = s; j < e; ++j) {
    const int c = colS[j];
    const float v = valS[j];
    const float4 tv = *(const float4*)&t1[(size_t)c * GH1 + p * 4];
    acc.x = fmaf(v, tv.x, acc.x);
    acc.y = fmaf(v, tv.y, acc.y);
    acc.z = fmaf(v, tv.z, acc.z);
    acc.w = fmaf(v, tv.w, acc.w);
  }
  *(float4*)&h1[(size_t)row * GH1 + p * 4] = acc;
}

// ---------------- mu_pre/lv_pre = relu(h1) @ gc2W / gc3W ----------------
__global__ __launch_bounds__(256) void k_h1gc(
    const float* __restrict__ h1, const float* __restrict__ gc2W, const float* __restrict__ gc3W,
    float* __restrict__ mp, float* __restrict__ lp)
{
  const int row = blockIdx.x * blockDim.x + threadIdx.x;
  if (row >= NROWS) return;
  float h[GH1];
  const float4* hr = (const float4*)(h1 + (size_t)row * GH1);
#pragma unroll
  for (int i = 0; i < GH1/4; ++i) ((float4*)h)[i] = hr[i];
#pragma unroll
  for (int k = 0; k < GH1; ++k) h[k] = fmaxf(h[k], 0.f);

  float m[GH2], l[GH2];
#pragma unroll
  for (int j = 0; j < GH2; ++j) { m[j] = 0.f; l[j] = 0.f; }
#pragma unroll
  for (int k = 0; k < GH1; ++k) {
    const float hv = h[k];
#pragma unroll
    for (int j = 0; j < GH2; ++j) {
      m[j] = fmaf(hv, gc2W[k*GH2 + j], m[j]);
      l[j] = fmaf(hv, gc3W[k*GH2 + j], l[j]);
    }
  }
  float4* mo = (float4*)(mp + (size_t)row * GH2);
  float4* lo = (float4*)(lp + (size_t)row * GH2);
  mo[0] = ((float4*)m)[0]; mo[1] = ((float4*)m)[1];
  lo[0] = ((float4*)l)[0]; lo[1] = ((float4*)l)[1];
}

// ---------------- spmm2 gather: mu/lv, 4 thr/row ----------------
__global__ __launch_bounds__(256) void k_spmm2g(
    const int* __restrict__ start, const int* __restrict__ colS, const float* __restrict__ valS,
    const float* __restrict__ mp, const float* __restrict__ lp,
    float* __restrict__ mu, float* __restrict__ lv)
{
  const int tid = threadIdx.x;
  const int row = blockIdx.x * 64 + (tid >> 2);
  const int p = tid & 3;
  if (row >= NROWS) return;
  const float* src = (p < 2) ? mp : lp;
  float* dst = (p < 2) ? mu : lv;
  const int off = (p & 1) * 4;
  const int s = start[row], e = start[row + 1];
  float4 acc = make_float4(0.f, 0.f, 0.f, 0.f);
  for (int j = s; j < e; ++j) {
    const int c = colS[j];
    const float v = valS[j];
    const float4 sv = *(const float4*)&src[(size_t)c * GH2 + off];
    acc.x = fmaf(v, sv.x, acc.x);
    acc.y = fmaf(v, sv.y, acc.y);
    acc.z = fmaf(v, sv.z, acc.z);
    acc.w = fmaf(v, sv.w, acc.w);
  }
  *(float4*)&dst[(size_t)row * GH2 + off] = acc;
}

// ---------------- z = [feat_x | mu]; gnn_z = mu; q = student-t ----------------
__global__ __launch_bounds__(256) void k_zq(
    const float* __restrict__ fx, const float* __restrict__ mu, const float* __restrict__ clus,
    float* __restrict__ z_o, float* __restrict__ gz_o, float* __restrict__ q_o)
{
  const int row = blockIdx.x * blockDim.x + threadIdx.x;
  if (row >= NROWS) return;
  float z[LAT];
  const float4* f4 = (const float4*)(fx + (size_t)row * FH2);
#pragma unroll
  for (int i = 0; i < FH2/4; ++i) ((float4*)z)[i] = f4[i];
  const float4* m4 = (const float4*)(mu + (size_t)row * GH2);
  ((float4*)z)[5] = m4[0];
  ((float4*)z)[6] = m4[1];

  float4* zo = (float4*)(z_o + (size_t)row * LAT);
#pragma unroll
  for (int i = 0; i < LAT/4; ++i) zo[i] = ((float4*)z)[i];
  float4* go = (float4*)(gz_o + (size_t)row * GH2);
  go[0] = m4[0]; go[1] = m4[1];

  float q[KCL];
  float ssum = 0.f;
#pragma unroll
  for (int j = 0; j < KCL; ++j) {
    float d = 0.f;
#pragma unroll
    for (int k = 0; k < LAT; ++k) {
      const float df = z[k] - clus[j*LAT + k];
      d = fmaf(df, df, d);
    }
    q[j] = 1.f / (1.f + d);
    ssum += q[j];
  }
  const float inv = 1.f / ssum;
#pragma unroll
  for (int j = 0; j < KCL; ++j) q[j] *= inv;
  float2* qo = (float2*)(q_o + (size_t)row * KCL);
#pragma unroll
  for (int i = 0; i < KCL/2; ++i) qo[i] = ((float2*)q)[i];
}

// ---------------- decoder (reverted best): 16 rows x 256 cols per block, LDS-staged ----------------
__global__ __launch_bounds__(256) void k_dec(
    const float* __restrict__ z, const float* __restrict__ W, const float* __restrict__ db,
    const float* __restrict__ g3, const float* __restrict__ bb3, float* __restrict__ out)
{
  __shared__ float Ws[LAT][256];   // 28 KB
  __shared__ float zs[16 * LAT];   // 1.75 KB

  const int tid = threadIdx.x;
  const int c0  = blockIdx.x * 256;
  const int r0  = blockIdx.y * 16;

#pragma unroll
  for (int rep = 0; rep < 7; ++rep) {
    const int f4 = rep * 256 + tid;
    const int k  = f4 >> 6;
    const int cg = (f4 & 63) * 4;
    float4 v = make_float4(0.f, 0.f, 0.f, 0.f);
    if (c0 + cg < DIN) v = *(const float4*)&W[(size_t)k * DIN + c0 + cg];
    *(float4*)&Ws[k][cg] = v;
  }
  if (tid < 112) {
    *(float4*)&zs[tid * 4] = *(const float4*)&z[(size_t)r0 * LAT + tid * 4];
  }
  __syncthreads();

  const int w    = tid >> 6;
  const int lane = tid & 63;
  const int cl   = lane * 4;
  const int rloc = w * 4;

  float acc[4][4];
#pragma unroll
  for (int i = 0; i < 4; ++i)
#pragma unroll
    for (int j = 0; j < 4; ++j) acc[i][j] = 0.f;

#pragma unroll
  for (int k4 = 0; k4 < 7; ++k4) {
    float zq[4][4];
#pragma unroll
    for (int i = 0; i < 4; ++i)
      *(float4*)zq[i] = *(const float4*)&zs[(rloc + i) * LAT + k4 * 4];
#pragma unroll
    for (int kk = 0; kk < 4; ++kk) {
      const float4 wv = *(const float4*)&Ws[k4 * 4 + kk][cl];
#pragma unroll
      for (int i = 0; i < 4; ++i) {
        acc[i][0] = fmaf(zq[i][kk], wv.x, acc[i][0]);
        acc[i][1] = fmaf(zq[i][kk], wv.y, acc[i][1]);
        acc[i][2] = fmaf(zq[i][kk], wv.z, acc[i][2]);
        acc[i][3] = fmaf(zq[i][kk], wv.w, acc[i][3]);
      }
    }
  }

  if (c0 + cl >= DIN) return;
  const float4 db4 = *(const float4*)&db[c0 + cl];
  const float4 g4  = *(const float4*)&g3[c0 + cl];
  const float4 bb4 = *(const float4*)&bb3[c0 + cl];
#pragma unroll
  for (int i = 0; i < 4; ++i) {
    float4 v;
    v.x = elu1((acc[i][0] + db4.x) * (g4.x * BN_RS) + bb4.x);
    v.y = elu1((acc[i][1] + db4.y) * (g4.y * BN_RS) + bb4.y);
    v.z = elu1((acc[i][2] + db4.z) * (g4.z * BN_RS) + bb4.z);
    v.w = elu1((acc[i][3] + db4.w) * (g4.w * BN_RS) + bb4.w);
    *(float4*)&out[(size_t)(r0 + rloc + i) * DIN + c0 + cl] = v;
  }
}

extern "C" void kernel_launch(void* const* d_in, const int* in_sizes, int n_in,
                              void* d_out, int out_size, void* d_ws, size_t ws_size,
                              hipStream_t stream) {
  const float* x    = (const float*)d_in[0];
  const float* vals = (const float*)d_in[1];
  const float* W1   = (const float*)d_in[2];
  const float* b1   = (const float*)d_in[3];
  const float* g1   = (const float*)d_in[4];
  const float* bb1  = (const float*)d_in[5];
  const float* W2   = (const float*)d_in[6];
  const float* b2   = (const float*)d_in[7];
  const float* g2   = (const float*)d_in[8];
  const float* bb2  = (const float*)d_in[9];
  const float* gc1W = (const float*)d_in[10];
  const float* gc2W = (const float*)d_in[11];
  const float* gc3W = (const float*)d_in[12];
  const float* dW   = (const float*)d_in[13];
  const float* db   = (const float*)d_in[14];
  const float* g3   = (const float*)d_in[15];
  const float* bb3  = (const float*)d_in[16];
  const float* clus = (const float*)d_in[17];
  const int* erow   = (const int*)d_in[18];
  const int* ecol   = (const int*)d_in[19];

  float* out  = (float*)d_out;
  float* z_o  = out;
  float* mu_o = out + (size_t)NROWS * 28;
  float* lv_o = out + (size_t)NROWS * 36;
  float* de_o = out + (size_t)NROWS * 44;
  float* q_o  = out + (size_t)NROWS * 3044;
  float* fx_o = out + (size_t)NROWS * 3054;
  float* gz_o = out + (size_t)NROWS * 3074;

  // scratch lives inside the de_feat region (written last, fully overwritten)
  float* feat1 = de_o;                                   // [0, 100N)
  float* t1    = de_o + (size_t)NROWS * 100;             // [100N, 132N)
  float* h1    = de_o + (size_t)NROWS * 132;             // [132N, 164N)
  float* mp    = de_o + (size_t)NROWS * 164;             // [164N, 172N)
  float* lp    = de_o + (size_t)NROWS * 172;             // [172N, 180N)
  unsigned short* Wt = (unsigned short*)(de_o + (size_t)NROWS * 200);  // 128x3008 bf16 (rows 112+ staged, never consumed)
  int*   deg   = (int*)(de_o + (size_t)NROWS * 210);     // [210N, 211N)
  int*   cnt   = (int*)(de_o + (size_t)NROWS * 211);     // [211N, 212N)
  int*   startA= (int*)(de_o + (size_t)NROWS * 212);     // [212N, 214N)
  int*   colS  = (int*)(de_o + (size_t)NROWS * 214);     // [214N, 230N)
  float* valS  = de_o + (size_t)NROWS * 230;             // [230N, 246N)

  k_prepW<<<dim3(165), 256, 0, stream>>>(W1, Wt);
  k_gemm1<<<dim3(782), 256, 0, stream>>>(x, Wt, b1, g1, bb1, feat1);
  k_enc2_gc1<<<dim3((NROWS + 255) / 256), 256, 0, stream>>>(feat1, W2, b2, g2, bb2, gc1W, fx_o, t1);

  k_zero_i<<<dim3(128), 256, 0, stream>>>(deg, 2 * NROWS);
  k_hist<<<dim3((NEDGE + 255) / 256), 256, 0, stream>>>(erow, deg);
  k_scan<<<dim3(1), 1024, 0, stream>>>(deg, startA);
  k_scatter<<<dim3((NEDGE + 255) / 256), 256, 0, stream>>>(erow, ecol, vals, startA, cnt, colS, valS);

  k_spmm1g<<<dim3((NROWS + 31) / 32), 256, 0, stream>>>(startA, colS, valS, t1, h1);
  k_h1gc<<<dim3((NROWS + 255) / 256), 256, 0, stream>>>(h1, gc2W, gc3W, mp, lp);
  k_spmm2g<<<dim3((NROWS + 63) / 64), 256, 0, stream>>>(startA, colS, valS, mp, lp, mu_o, lv_o);
  k_zq<<<dim3((NROWS + 255) / 256), 256, 0, stream>>>(fx_o, mu_o, clus, z_o, gz_o, q_o);
  k_dec<<<dim3(12, 3125), 256, 0, stream>>>(z_o, dW, db, g3, bb3, de_o);
}